// Round 2
// baseline (412.718 us; speedup 1.0000x reference)
//
#include <hip/hip_runtime.h>

// ---------------------------------------------------------------------------
// DiagMatrixConstructionBlock: per-node equivariant tensor-product block.
// n=512 nodes, Fm=48, output (B=8, max_nodes=128, P=2, 192, 192) f32.
// Output is 302 MB, >99% zeros. Each (b,pos,p) slice has 48 diagonal 4x4
// blocks; every 192-float row has exactly one 4-aligned nonzero float4.
// Strategy: node_kernel computes per-node M-blocks (512 x 48 x 4 x 4) into
// ws; a single fused fill kernel writes the whole 302MB output once
// (zeros + M-block chunks). Timed window also contains harness re-poison
// (~264us, uncontrollable); our floor is the one 302MB write (~48us).
// ---------------------------------------------------------------------------

// path tables: PATHS = [(0,0,0),(0,1,1),(0,2,2),(1,0,1),(1,1,0),(1,1,2),
//                       (1,2,1),(2,0,2),(2,1,1),(2,2,0),(2,2,2)]
__device__ const int ZOFF[11] = {0,48,192,432,480,624,768,1008,1056,1200,1440}; // z buffer offsets (48*(2*l2+1) each)
__device__ const int NOFF[11] = {0,48,192,432,576,624,864,1008,1248,1392,1440}; // o-output enumeration offsets (48*(2*l3+1))
__device__ const int OOFF[11] = {0,144,720,288,48,960,432,1200,576,96,1440};    // where each path's out goes in os[]
__device__ const int PL2[11]  = {0,1,2,0,1,1,2,0,1,2,2};
__device__ const int PL3[11]  = {0,1,2,1,0,2,1,2,1,0,2};

// ---- real Clebsch-Gordan tables (Frobenius-normalized), verified in R0.
#define R10f 0.31622776601683794f   // 1/sqrt(10)
#define R30f 0.18257418583505536f   // 1/sqrt(30)
#define A70f 0.23904572186687872f   // 2/sqrt(70)
#define B70f 0.11952286093343936f   // 1/sqrt(70)
#define T70f 0.20701966780270626f   // sqrt(3/70)

__device__ const float CG112[3][3][5] = {
  {{0,0,-R30f,0,-R10f},{0,R10f,0,0,0},{R10f,0,0,0,0}},
  {{0,R10f,0,0,0},{0,0,2.0f*R30f,0,0},{0,0,0,R10f,0}},
  {{R10f,0,0,0,0},{0,0,0,R10f,0},{0,0,-R30f,0,R10f}}
};

__device__ const float CG121[3][5][3] = {
  {{0,0,-R10f},{0,-R10f,0},{R30f,0,0},{0,0,0},{R10f,0,0}},
  {{0,0,0},{-R10f,0,0},{0,-2.0f*R30f,0},{0,0,-R10f},{0,0,0}},
  {{-R10f,0,0},{0,0,0},{0,0,R30f},{0,-R10f,0},{0,0,-R10f}}
};

__device__ const float CG222[5][5][5] = {
  {{0,0,A70f,0,0},{0,0,0,-T70f,0},{A70f,0,0,0,0},{0,-T70f,0,0,0},{0,0,0,0,0}},
  {{0,0,0,-T70f,0},{0,0,-B70f,0,T70f},{0,-B70f,0,0,0},{-T70f,0,0,0,0},{0,T70f,0,0,0}},
  {{A70f,0,0,0,0},{0,-B70f,0,0,0},{0,0,-A70f,0,0},{0,0,0,-B70f,0},{0,0,0,0,A70f}},
  {{0,-T70f,0,0,0},{-T70f,0,0,0,0},{0,0,0,-B70f,0},{0,0,-B70f,0,-T70f},{0,0,0,-T70f,0}},
  {{0,0,0,0,0},{0,T70f,0,0,0},{0,0,0,0,A70f},{0,0,0,-T70f,0},{0,0,A70f,0,0}}
};

// ---------------------------------------------------------------------------
// Weff (transposed layouts for contiguous per-thread reads in node g-phase):
//   weff0T[(f*2+o)*144 + u] = sum_k Wo0[u,k*48+f]*Wt0[k,o] / 48
//   weff{1,2}T[f*192 + u]   = sum_k Wo_[u,k*48+f]*Wt_[k]   * (1/sqrt(192*16))
__global__ void weff_kernel(const float* __restrict__ Wo0, const float* __restrict__ Wo1,
                            const float* __restrict__ Wo2, const float* __restrict__ Wt0,
                            const float* __restrict__ Wt1, const float* __restrict__ Wt2,
                            float* __restrict__ weff0, float* __restrict__ weff1,
                            float* __restrict__ weff2) {
  int idx = blockIdx.x * 256 + threadIdx.x;
  const float s0  = 1.0f / 48.0f;                 // 1/sqrt(144) * 1/sqrt(16)
  const float s12 = 0.018042195912175807f;        // 1/sqrt(192) * 1/sqrt(16)
  if (idx < 13824) {                 // 144*48*2, enumerated as fo*144+u
    int u = idx % 144, fo = idx / 144;
    int f = fo >> 1, o = fo & 1;
    float acc = 0.0f;
    for (int k = 0; k < 16; ++k) acc += Wo0[u*768 + k*48 + f] * Wt0[k*2 + o];
    weff0[idx] = acc * s0;
  } else if (idx < 23040) {          // +192*48, enumerated as f*192+u
    int j = idx - 13824; int u = j % 192, f = j / 192;
    float acc = 0.0f;
    for (int k = 0; k < 16; ++k) acc += Wo1[u*768 + k*48 + f] * Wt1[k];
    weff1[j] = acc * s12;
  } else if (idx < 32256) {
    int j = idx - 23040; int u = j % 192, f = j / 192;
    float acc = 0.0f;
    for (int k = 0; k < 16; ++k) acc += Wo2[u*768 + k*48 + f] * Wt2[k];
    weff2[j] = acc * s12;
  }
}

// starts[b] = #nodes with batch < b, for b in [0,9). pos = node - starts[batch].
__global__ void starts_kernel(const int* __restrict__ batch, int n, int* __restrict__ starts) {
  int b = threadIdx.x;
  if (b < 9) {
    int c = 0;
    for (int i = 0; i < n; ++i) c += (batch[i] < b) ? 1 : 0;
    starts[b] = c;
  }
}

// ---------------------------------------------------------------------------
// Per-node chain: x -> y -> z (per-path) -> CG contraction -> Weff -> M-blocks.
// Writes mblk[node][f][i][0..3] (float4 per (f,i)).
__global__ __launch_bounds__(256) void node_kernel(
    const float* __restrict__ feats, const float* __restrict__ Wl0,
    const float* __restrict__ Wl1, const float* __restrict__ Wl2,
    const float* __restrict__ tpw, const float* __restrict__ weff0,
    const float* __restrict__ weff1, const float* __restrict__ weff2,
    float* __restrict__ mblk) {
  const int node = blockIdx.x;
  const int tid = threadIdx.x;
  const float sF = 0.14433756729740643f;  // 1/sqrt(48)

  __shared__ float xs[432];   // x0[48] | x1[48][3] | x2[48][5]
  __shared__ float ys[432];   // y, same layout
  __shared__ float zs[1680];  // per-path tp_w @ y_l2
  __shared__ float os[1680];  // o0[3*48] | o1[4*48][3] | o2[4*48][5]
  __shared__ float gs[480];   // g0[48][2] | g1[48][3] | g2[48][5]

  const float* fr = feats + node * 432;
  for (int t = tid; t < 432; t += 256) xs[t] = fr[t];
  __syncthreads();

  // y[l] = (x[l]^T W_lin_l) * sF
  for (int t = tid; t < 432; t += 256) {
    float acc = 0.0f;
    if (t < 48) {
      int v = t;
      for (int u = 0; u < 48; ++u) acc += xs[u] * Wl0[u*48 + v];
    } else if (t < 192) {
      int j = t - 48, v = j / 3, i = j % 3;
      for (int u = 0; u < 48; ++u) acc += xs[48 + u*3 + i] * Wl1[u*48 + v];
    } else {
      int j = t - 192, v = j / 5, i = j % 5;
      for (int u = 0; u < 48; ++u) acc += xs[192 + u*5 + i] * Wl2[u*48 + v];
    }
    ys[t] = acc * sF;
  }
  __syncthreads();

  // z[p][u][k] = sF * sum_v tp_w[p][u][v] * y_l2[v][k]
  for (int t = tid; t < 1680; t += 256) {
    int p = 10; while (ZOFF[p] > t) --p;
    int j = t - ZOFF[p];
    int l2 = PL2[p], K2 = 2*l2 + 1;
    int u = j / K2, k = j % K2;
    const float* tw = tpw + p*2304 + u*48;
    const float* yy = ys + (l2 == 0 ? 0 : (l2 == 1 ? 48 : 192));
    float acc = 0.0f;
    for (int v = 0; v < 48; ++v) acc += tw[v] * yy[v*K2 + k];
    zs[t] = acc * sF;
  }
  __syncthreads();

  // out_p[u][c] = sum_{m,k} y_l1[u][m] * z_p[u][k] * CG[m][k][c]
  for (int t = tid; t < 1680; t += 256) {
    int p = 10; while (NOFF[p] > t) --p;
    int j = t - NOFF[p];
    int K3 = 2*PL3[p] + 1;
    int u = j / K3, c = j % K3;
    const float* zp = zs + ZOFF[p];
    float acc = 0.0f;
    switch (p) {
      case 0: acc = ys[u] * zp[u]; break;
      case 1: acc = 0.5773502691896258f * ys[u] * zp[u*3 + c]; break;
      case 2: acc = 0.4472135954999579f * ys[u] * zp[u*5 + c]; break;
      case 3: acc = 0.5773502691896258f * ys[48 + u*3 + c] * zp[u]; break;
      case 4: { float s = 0.0f;
                for (int m = 0; m < 3; ++m) s += ys[48 + u*3 + m] * zp[u*3 + m];
                acc = -0.5773502691896258f * s; } break;
      case 5: for (int m = 0; m < 3; ++m)
                for (int k = 0; k < 3; ++k)
                  acc += ys[48 + u*3 + m] * zp[u*3 + k] * CG112[m][k][c];
              break;
      case 6: for (int m = 0; m < 3; ++m)
                for (int k = 0; k < 5; ++k)
                  acc += ys[48 + u*3 + m] * zp[u*5 + k] * CG121[m][k][c];
              break;
      case 7: acc = 0.4472135954999579f * ys[192 + u*5 + c] * zp[u]; break;
      case 8: for (int m = 0; m < 5; ++m)   // CG211[m][k][c] = CG121[k][m][c]
                for (int k = 0; k < 3; ++k)
                  acc += ys[192 + u*5 + m] * zp[u*3 + k] * CG121[k][m][c];
              break;
      case 9: { float s = 0.0f;
                for (int m = 0; m < 5; ++m) s += ys[192 + u*5 + m] * zp[u*5 + m];
                acc = 0.4472135954999579f * s; } break;
      default: for (int m = 0; m < 5; ++m)
                 for (int k = 0; k < 5; ++k)
                   acc += ys[192 + u*5 + m] * zp[u*5 + k] * CG222[m][k][c];
               break;
    }
    os[OOFF[p] + u*K3 + c] = acc;
  }
  __syncthreads();

  // g = o @ WeffT (scales folded; contiguous per-thread weight rows)
  for (int t = tid; t < 480; t += 256) {
    float acc = 0.0f;
    if (t < 96) {
      const float* w = weff0 + t * 144;
      for (int u = 0; u < 144; ++u) acc += os[u] * w[u];
    } else if (t < 240) {
      int j = t - 96, f = j / 3, i = j % 3;
      const float* w = weff1 + f * 192;
      for (int u = 0; u < 192; ++u) acc += os[144 + u*3 + i] * w[u];
    } else {
      int j = t - 240, f = j / 5, m = j % 5;
      const float* w = weff2 + f * 192;
      for (int u = 0; u < 192; ++u) acc += os[720 + u*5 + m] * w[u];
    }
    gs[t] = acc;
  }
  __syncthreads();

  // M-blocks: mblk[node][f*16 + i*4 + 0..3]
  if (tid < 192) {
    int f = tid >> 2, i = tid & 3;
    float a0 = gs[f*2 + 0], a1 = gs[f*2 + 1];
    float v0 = gs[96 + f*3 + 0], v1 = gs[96 + f*3 + 1], v2 = gs[96 + f*3 + 2];
    float d0 = gs[240 + f*5 + 0], d1 = gs[240 + f*5 + 1], d2 = gs[240 + f*5 + 2];
    float d3 = gs[240 + f*5 + 3], d4 = gs[240 + f*5 + 4];
    const float R3i = 0.5773502691896258f;  // 1/sqrt(3)
    float m0, m1, m2, m3;
    if (i == 0)      { m0 = a0; m1 = v0; m2 = v1; m3 = v2; }
    else if (i == 1) { m0 = v0; m1 = a1*R3i - R30f*d2 - R10f*d4; m2 = R10f*d1; m3 = R10f*d0; }
    else if (i == 2) { m0 = v1; m1 = R10f*d1; m2 = a1*R3i + 2.0f*R30f*d2; m3 = R10f*d3; }
    else             { m0 = v2; m1 = R10f*d0; m2 = R10f*d3; m3 = a1*R3i - R30f*d2 + R10f*d4; }
    *(float4*)(mblk + node * 768 + (tid << 2)) = make_float4(m0, m1, m2, m3);
  }
}

// ---------------------------------------------------------------------------
// Fused zero-fill + scatter: one pass over the whole 302MB output.
// grid = (9, max_nodes, 8); each block owns one (b,pos) pair's 73728 floats
// /8... (9 blocks x 256 thr x 8 float4 = 18432 float4 = 73728 floats).
// Within (b,pos): float4 chunk idx -> j=idx%48 (col block), row=(idx/48)%192,
// p=idx/9216 (implicit in address). Nonzero iff j == row/4 and node valid.
__global__ __launch_bounds__(256) void fill_kernel(const float* __restrict__ mblk,
                                                   const int* __restrict__ starts,
                                                   float* __restrict__ out) {
  const int tid = threadIdx.x;
  const int b = blockIdx.z, pos = blockIdx.y;
  const int s0 = starts[b], s1 = starts[b + 1];
  const int node = s0 + pos;
  const bool valid = node < s1;
  float* dst = out + (size_t)(b * gridDim.y + pos) * 73728u;
  const float4 zero = make_float4(0.f, 0.f, 0.f, 0.f);
  const int base = blockIdx.x * 2048 + tid;
  #pragma unroll
  for (int k = 0; k < 8; ++k) {
    int idx = base + k * 256;
    int j = idx % 48;
    int row = (idx / 48) % 192;
    float4 val = zero;
    if (valid && j == (row >> 2)) {
      val = *(const float4*)(mblk + node * 768 + (row << 2));
    }
    *(float4*)(dst + (size_t)idx * 4) = val;
  }
}

// ---------------------------------------------------------------------------
extern "C" void kernel_launch(void* const* d_in, const int* in_sizes, int n_in,
                              void* d_out, int out_size, void* d_ws, size_t ws_size,
                              hipStream_t stream) {
  const float* feats = (const float*)d_in[0];
  const float* Wl0   = (const float*)d_in[1];
  const float* Wl1   = (const float*)d_in[2];
  const float* Wl2   = (const float*)d_in[3];
  const float* tpw   = (const float*)d_in[4];
  const float* Wo0   = (const float*)d_in[5];
  const float* Wo1   = (const float*)d_in[6];
  const float* Wo2   = (const float*)d_in[7];
  const float* Wt0   = (const float*)d_in[8];
  const float* Wt1   = (const float*)d_in[9];
  const float* Wt2   = (const float*)d_in[10];
  const int*   batch = (const int*)d_in[11];

  int n = in_sizes[0] / 432;                        // 512
  int max_nodes = out_size / (8 * 2 * 192 * 192);   // 128

  // ws layout (floats): weff0T [13824) | weff1T [23040) | weff2T [32256)
  //                     | starts int[9] @32256 | mblk @32272 (16B aligned)
  float* ws     = (float*)d_ws;
  float* weff0  = ws;
  float* weff1  = ws + 13824;
  float* weff2  = ws + 23040;
  int*   starts = (int*)(ws + 32256);
  float* mblk   = ws + 32272;

  weff_kernel<<<126, 256, 0, stream>>>(Wo0, Wo1, Wo2, Wt0, Wt1, Wt2, weff0, weff1, weff2);
  starts_kernel<<<1, 64, 0, stream>>>(batch, n, starts);
  node_kernel<<<n, 256, 0, stream>>>(feats, Wl0, Wl1, Wl2, tpw, weff0, weff1, weff2, mblk);
  fill_kernel<<<dim3(9, max_nodes, 8), 256, 0, stream>>>(mblk, starts, (float*)d_out);
}

// Round 4
// 407.528 us; speedup vs baseline: 1.0127x; 1.0127x over previous
//
#include <hip/hip_runtime.h>

// ---------------------------------------------------------------------------
// DiagMatrixConstructionBlock: per-node equivariant tensor-product block.
// n=512 nodes, Fm=48, output (B=8, max_nodes=128, P=2, 192, 192) f32.
// Output is 302 MB, >99% zeros. Each (b,pos,p) slice has 48 diagonal 4x4
// blocks; every 192-float row has exactly one 4-aligned nonzero float4.
// Pipeline: prep (Weff fold + segment starts) -> node (per-node chain ->
// 48x4x4 M-blocks in ws) -> fill (single fused 302MB zero+scatter pass,
// nontemporal stores). Timed window also contains harness re-poison of
// d_ws (1.2GB ~205us) + d_out (302MB ~50us) — uncontrollable floor.
// ---------------------------------------------------------------------------

typedef float f32x4 __attribute__((ext_vector_type(4)));

// path tables: PATHS = [(0,0,0),(0,1,1),(0,2,2),(1,0,1),(1,1,0),(1,1,2),
//                       (1,2,1),(2,0,2),(2,1,1),(2,2,0),(2,2,2)]
__device__ const int ZOFF[11] = {0,48,192,432,480,624,768,1008,1056,1200,1440}; // z buffer offsets (48*(2*l2+1) each)
__device__ const int NOFF[11] = {0,48,192,432,576,624,864,1008,1248,1392,1440}; // o-output enumeration offsets (48*(2*l3+1))
__device__ const int OOFF[11] = {0,144,720,288,48,960,432,1200,576,96,1440};    // where each path's out goes in os[]
__device__ const int PL2[11]  = {0,1,2,0,1,1,2,0,1,2,2};
__device__ const int PL3[11]  = {0,1,2,1,0,2,1,2,1,0,2};

// ---- real Clebsch-Gordan tables (Frobenius-normalized), verified in R1.
#define R10f 0.31622776601683794f   // 1/sqrt(10)
#define R30f 0.18257418583505536f   // 1/sqrt(30)
#define A70f 0.23904572186687872f   // 2/sqrt(70)
#define B70f 0.11952286093343936f   // 1/sqrt(70)
#define T70f 0.20701966780270626f   // sqrt(3/70)

__device__ const float CG112[3][3][5] = {
  {{0,0,-R30f,0,-R10f},{0,R10f,0,0,0},{R10f,0,0,0,0}},
  {{0,R10f,0,0,0},{0,0,2.0f*R30f,0,0},{0,0,0,R10f,0}},
  {{R10f,0,0,0,0},{0,0,0,R10f,0},{0,0,-R30f,0,R10f}}
};

__device__ const float CG121[3][5][3] = {
  {{0,0,-R10f},{0,-R10f,0},{R30f,0,0},{0,0,0},{R10f,0,0}},
  {{0,0,0},{-R10f,0,0},{0,-2.0f*R30f,0},{0,0,-R10f},{0,0,0}},
  {{-R10f,0,0},{0,0,0},{0,0,R30f},{0,-R10f,0},{0,0,-R10f}}
};

__device__ const float CG222[5][5][5] = {
  {{0,0,A70f,0,0},{0,0,0,-T70f,0},{A70f,0,0,0,0},{0,-T70f,0,0,0},{0,0,0,0,0}},
  {{0,0,0,-T70f,0},{0,0,-B70f,0,T70f},{0,-B70f,0,0,0},{-T70f,0,0,0,0},{0,T70f,0,0,0}},
  {{A70f,0,0,0,0},{0,-B70f,0,0,0},{0,0,-A70f,0,0},{0,0,0,-B70f,0},{0,0,0,0,A70f}},
  {{0,-T70f,0,0,0},{-T70f,0,0,0,0},{0,0,0,-B70f,0},{0,0,-B70f,0,-T70f},{0,0,0,-T70f,0}},
  {{0,0,0,0,0},{0,T70f,0,0,0},{0,0,0,0,A70f},{0,0,0,-T70f,0},{0,0,A70f,0,0}}
};

// ---------------------------------------------------------------------------
// Prep: Weff fold (blocks 0..125) + segment starts (block 126).
//   weff0T[(f*2+o)*144 + u] = sum_k Wo0[u,k*48+f]*Wt0[k,o] / 48
//   weff{1,2}T[f*192 + u]   = sum_k Wo_[u,k*48+f]*Wt_[k]   * (1/sqrt(192*16))
//   starts[b] = #nodes with batch < b, b in [0,9); pos = node - starts[batch].
__global__ __launch_bounds__(256) void prep_kernel(
    const float* __restrict__ Wo0, const float* __restrict__ Wo1,
    const float* __restrict__ Wo2, const float* __restrict__ Wt0,
    const float* __restrict__ Wt1, const float* __restrict__ Wt2,
    const int* __restrict__ batch, int n,
    float* __restrict__ weff0, float* __restrict__ weff1,
    float* __restrict__ weff2, int* __restrict__ starts) {
  int idx = blockIdx.x * 256 + threadIdx.x;
  const float s0  = 1.0f / 48.0f;                 // 1/sqrt(144) * 1/sqrt(16)
  const float s12 = 0.018042195912175807f;        // 1/sqrt(192) * 1/sqrt(16)
  if (idx < 13824) {                 // 144*48*2, enumerated as fo*144+u
    int u = idx % 144, fo = idx / 144;
    int f = fo >> 1, o = fo & 1;
    float acc = 0.0f;
    #pragma unroll
    for (int k = 0; k < 16; ++k) acc += Wo0[u*768 + k*48 + f] * Wt0[k*2 + o];
    weff0[idx] = acc * s0;
  } else if (idx < 23040) {          // +192*48, enumerated as f*192+u
    int j = idx - 13824; int u = j % 192, f = j / 192;
    float acc = 0.0f;
    #pragma unroll
    for (int k = 0; k < 16; ++k) acc += Wo1[u*768 + k*48 + f] * Wt1[k];
    weff1[j] = acc * s12;
  } else if (idx < 32256) {
    int j = idx - 23040; int u = j % 192, f = j / 192;
    float acc = 0.0f;
    #pragma unroll
    for (int k = 0; k < 16; ++k) acc += Wo2[u*768 + k*48 + f] * Wt2[k];
    weff2[j] = acc * s12;
  } else if (blockIdx.x == 126 && threadIdx.x < 9) {
    int b = threadIdx.x, c = 0;
    for (int i = 0; i < n; ++i) c += (batch[i] < b) ? 1 : 0;
    starts[b] = c;
  }
}

// ---------------------------------------------------------------------------
// Per-node chain: x -> y -> z (per-path) -> CG contraction -> Weff -> M-blocks.
// Writes mblk[node][f][i][0..3] (float4 per (f,i)).
__global__ __launch_bounds__(256) void node_kernel(
    const float* __restrict__ feats, const float* __restrict__ Wl0,
    const float* __restrict__ Wl1, const float* __restrict__ Wl2,
    const float* __restrict__ tpw, const float* __restrict__ weff0,
    const float* __restrict__ weff1, const float* __restrict__ weff2,
    float* __restrict__ mblk) {
  const int node = blockIdx.x;
  const int tid = threadIdx.x;
  const float sF = 0.14433756729740643f;  // 1/sqrt(48)

  __shared__ float xs[432];   // x0[48] | x1[48][3] | x2[48][5]
  __shared__ float ys[432];   // y, same layout
  __shared__ float zs[1680];  // per-path tp_w @ y_l2
  __shared__ float os[1680];  // o0[3*48] | o1[4*48][3] | o2[4*48][5]
  __shared__ float gs[480];   // g0[48][2] | g1[48][3] | g2[48][5]

  const float* fr = feats + node * 432;
  for (int t = tid; t < 432; t += 256) xs[t] = fr[t];
  __syncthreads();

  // y[l] = (x[l]^T W_lin_l) * sF
  for (int t = tid; t < 432; t += 256) {
    float acc = 0.0f;
    if (t < 48) {
      int v = t;
      #pragma unroll
      for (int u = 0; u < 48; ++u) acc += xs[u] * Wl0[u*48 + v];
    } else if (t < 192) {
      int j = t - 48, v = j / 3, i = j % 3;
      #pragma unroll
      for (int u = 0; u < 48; ++u) acc += xs[48 + u*3 + i] * Wl1[u*48 + v];
    } else {
      int j = t - 192, v = j / 5, i = j % 5;
      #pragma unroll
      for (int u = 0; u < 48; ++u) acc += xs[192 + u*5 + i] * Wl2[u*48 + v];
    }
    ys[t] = acc * sF;
  }
  __syncthreads();

  // z[p][u][k] = sF * sum_v tp_w[p][u][v] * y_l2[v][k]
  for (int t = tid; t < 1680; t += 256) {
    int p = 10; while (ZOFF[p] > t) --p;
    int j = t - ZOFF[p];
    int l2 = PL2[p], K2 = 2*l2 + 1;
    int u = j / K2, k = j % K2;
    const float* tw = tpw + p*2304 + u*48;
    const float* yy = ys + (l2 == 0 ? 0 : (l2 == 1 ? 48 : 192));
    float acc = 0.0f;
    #pragma unroll
    for (int v = 0; v < 48; ++v) acc += tw[v] * yy[v*K2 + k];
    zs[t] = acc * sF;
  }
  __syncthreads();

  // out_p[u][c] = sum_{m,k} y_l1[u][m] * z_p[u][k] * CG[m][k][c]
  for (int t = tid; t < 1680; t += 256) {
    int p = 10; while (NOFF[p] > t) --p;
    int j = t - NOFF[p];
    int K3 = 2*PL3[p] + 1;
    int u = j / K3, c = j % K3;
    const float* zp = zs + ZOFF[p];
    float acc = 0.0f;
    switch (p) {
      case 0: acc = ys[u] * zp[u]; break;
      case 1: acc = 0.5773502691896258f * ys[u] * zp[u*3 + c]; break;
      case 2: acc = 0.4472135954999579f * ys[u] * zp[u*5 + c]; break;
      case 3: acc = 0.5773502691896258f * ys[48 + u*3 + c] * zp[u]; break;
      case 4: { float s = 0.0f;
                #pragma unroll
                for (int m = 0; m < 3; ++m) s += ys[48 + u*3 + m] * zp[u*3 + m];
                acc = -0.5773502691896258f * s; } break;
      case 5: {
                #pragma unroll
                for (int m = 0; m < 3; ++m) {
                  #pragma unroll
                  for (int k = 0; k < 3; ++k)
                    acc += ys[48 + u*3 + m] * zp[u*3 + k] * CG112[m][k][c];
                }
              } break;
      case 6: {
                #pragma unroll
                for (int m = 0; m < 3; ++m) {
                  #pragma unroll
                  for (int k = 0; k < 5; ++k)
                    acc += ys[48 + u*3 + m] * zp[u*5 + k] * CG121[m][k][c];
                }
              } break;
      case 7: acc = 0.4472135954999579f * ys[192 + u*5 + c] * zp[u]; break;
      case 8: {
                #pragma unroll
                for (int m = 0; m < 5; ++m) {   // CG211[m][k][c] = CG121[k][m][c]
                  #pragma unroll
                  for (int k = 0; k < 3; ++k)
                    acc += ys[192 + u*5 + m] * zp[u*3 + k] * CG121[k][m][c];
                }
              } break;
      case 9: { float s = 0.0f;
                #pragma unroll
                for (int m = 0; m < 5; ++m) s += ys[192 + u*5 + m] * zp[u*5 + m];
                acc = 0.4472135954999579f * s; } break;
      default: {
                #pragma unroll
                for (int m = 0; m < 5; ++m) {
                  #pragma unroll
                  for (int k = 0; k < 5; ++k)
                    acc += ys[192 + u*5 + m] * zp[u*5 + k] * CG222[m][k][c];
                }
              } break;
    }
    os[OOFF[p] + u*K3 + c] = acc;
  }
  __syncthreads();

  // g = o @ WeffT (scales folded; per-thread contiguous weight rows, L2-hot)
  for (int t = tid; t < 480; t += 256) {
    float acc = 0.0f;
    if (t < 96) {
      const float* w = weff0 + t * 144;
      #pragma unroll 4
      for (int u = 0; u < 144; ++u) acc += os[u] * w[u];
    } else if (t < 240) {
      int j = t - 96, f = j / 3, i = j % 3;
      const float* w = weff1 + f * 192;
      #pragma unroll 4
      for (int u = 0; u < 192; ++u) acc += os[144 + u*3 + i] * w[u];
    } else {
      int j = t - 240, f = j / 5, m = j % 5;
      const float* w = weff2 + f * 192;
      #pragma unroll 4
      for (int u = 0; u < 192; ++u) acc += os[720 + u*5 + m] * w[u];
    }
    gs[t] = acc;
  }
  __syncthreads();

  // M-blocks: mblk[node][f*16 + i*4 + 0..3]
  if (tid < 192) {
    int f = tid >> 2, i = tid & 3;
    float a0 = gs[f*2 + 0], a1 = gs[f*2 + 1];
    float v0 = gs[96 + f*3 + 0], v1 = gs[96 + f*3 + 1], v2 = gs[96 + f*3 + 2];
    float d0 = gs[240 + f*5 + 0], d1 = gs[240 + f*5 + 1], d2 = gs[240 + f*5 + 2];
    float d3 = gs[240 + f*5 + 3], d4 = gs[240 + f*5 + 4];
    const float R3i = 0.5773502691896258f;  // 1/sqrt(3)
    float m0, m1, m2, m3;
    if (i == 0)      { m0 = a0; m1 = v0; m2 = v1; m3 = v2; }
    else if (i == 1) { m0 = v0; m1 = a1*R3i - R30f*d2 - R10f*d4; m2 = R10f*d1; m3 = R10f*d0; }
    else if (i == 2) { m0 = v1; m1 = R10f*d1; m2 = a1*R3i + 2.0f*R30f*d2; m3 = R10f*d3; }
    else             { m0 = v2; m1 = R10f*d0; m2 = R10f*d3; m3 = a1*R3i - R30f*d2 + R10f*d4; }
    *(float4*)(mblk + node * 768 + (tid << 2)) = make_float4(m0, m1, m2, m3);
  }
}

// ---------------------------------------------------------------------------
// Fused zero-fill + scatter: one pass over the whole 302MB output.
// grid = (9, max_nodes, 8); each block owns 1/9 of one (b,pos) pair's
// 73728 floats (9 x 256 thr x 8 float4). Within (b,pos): float4 chunk idx ->
// j=idx%48 (col block), row=(idx/48)%192. Nonzero iff j==row/4 and node valid.
// Nontemporal stores: pure streaming write, no reuse.
__global__ __launch_bounds__(256) void fill_kernel(const float* __restrict__ mblk,
                                                   const int* __restrict__ starts,
                                                   float* __restrict__ out) {
  const int tid = threadIdx.x;
  const int b = blockIdx.z, pos = blockIdx.y;
  const int s0 = starts[b], s1 = starts[b + 1];
  const int node = s0 + pos;
  const bool valid = node < s1;
  float* dst = out + (size_t)(b * gridDim.y + pos) * 73728u;
  const int base = blockIdx.x * 2048 + tid;
  #pragma unroll
  for (int k = 0; k < 8; ++k) {
    int idx = base + k * 256;
    int j = idx % 48;
    int row = (idx / 48) % 192;
    f32x4 val = (f32x4)0.0f;
    if (valid && j == (row >> 2)) {
      val = *(const f32x4*)(mblk + node * 768 + (row << 2));
    }
    __builtin_nontemporal_store(val, (f32x4*)(dst + (size_t)idx * 4));
  }
}

// ---------------------------------------------------------------------------
extern "C" void kernel_launch(void* const* d_in, const int* in_sizes, int n_in,
                              void* d_out, int out_size, void* d_ws, size_t ws_size,
                              hipStream_t stream) {
  const float* feats = (const float*)d_in[0];
  const float* Wl0   = (const float*)d_in[1];
  const float* Wl1   = (const float*)d_in[2];
  const float* Wl2   = (const float*)d_in[3];
  const float* tpw   = (const float*)d_in[4];
  const float* Wo0   = (const float*)d_in[5];
  const float* Wo1   = (const float*)d_in[6];
  const float* Wo2   = (const float*)d_in[7];
  const float* Wt0   = (const float*)d_in[8];
  const float* Wt1   = (const float*)d_in[9];
  const float* Wt2   = (const float*)d_in[10];
  const int*   batch = (const int*)d_in[11];

  int n = in_sizes[0] / 432;                        // 512
  int max_nodes = out_size / (8 * 2 * 192 * 192);   // 128

  // ws layout (floats): weff0T [13824) | weff1T [23040) | weff2T [32256)
  //                     | starts int[9] @32256 | mblk @32272 (16B aligned)
  float* ws     = (float*)d_ws;
  float* weff0  = ws;
  float* weff1  = ws + 13824;
  float* weff2  = ws + 23040;
  int*   starts = (int*)(ws + 32256);
  float* mblk   = ws + 32272;

  prep_kernel<<<127, 256, 0, stream>>>(Wo0, Wo1, Wo2, Wt0, Wt1, Wt2, batch, n,
                                       weff0, weff1, weff2, starts);
  node_kernel<<<n, 256, 0, stream>>>(feats, Wl0, Wl1, Wl2, tpw, weff0, weff1, weff2, mblk);
  fill_kernel<<<dim3(9, max_nodes, 8), 256, 0, stream>>>(mblk, starts, (float*)d_out);
}